// Round 4
// baseline (652.499 us; speedup 1.0000x reference)
//
#include <hip/hip_runtime.h>
#include <math.h>

#define CIN 256
#define COUT 256
#define NB 8
#define HID 128
#define HW 4096
#define BATCH 64

#define TROWS 18    // 16 output rows + 2 halo
#define XS 64       // row stride in LDS: no pads; col halo via lane shuffles

typedef float f32x4 __attribute__((ext_vector_type(4)));  // native vec for nt-store

// ---------------- K0: repack base_filters [n][c*9+d] -> fT[(c*9+d)*8+n] ----
__global__ __launch_bounds__(256) void repack_filters(
    const float* __restrict__ bf, float* __restrict__ fT) {
  int i = blockIdx.x * 256 + threadIdx.x;  // over 8*2304 = 18432
  if (i < 8 * 2304) {
    int n = i / 2304;
    int cd = i % 2304;
    fT[cd * 8 + n] = bf[i];
  }
}

// ---------------- K1: conv (x -> ypart) + pooling partials -----------------
// grid 1024: bid = b*16 + g*4 + rc. block 256, 4 blocks/CU (LDS 36.9KB)
// Block: 64 channels (group g), 16 output rows (chunk rc), 8 filters, 64 cols.
// Thread: 8 filters x 4 cols (one row) = 32 fp32 accumulators.
// v4: amdgpu_waves_per_eu(4,4) — v2/v3 were silently capped at 64 VGPRs
// (RA targeted 8 waves/EU), which spilled the 36-VGPR prefetch to scratch
// (WRITE_SIZE 235 MB vs 35 MB real). LDS already caps us at 4 blocks/CU,
// so pinning 4 waves/EU costs nothing and raises the VGPR budget to 128.
// Keeps v3's conflict-free LDS (bank conflicts: 2.1e7 -> 0) + pinned prefetch.
__global__ __launch_bounds__(256)
__attribute__((amdgpu_waves_per_eu(4, 4))) void conv_pool_kernel(
    const float* __restrict__ x, const float* __restrict__ fT,
    float* __restrict__ ypart, float* __restrict__ poolpart) {
  __shared__ float xs[8 * TROWS * XS];  // 36,864 B
  const int t = threadIdx.x;
  const int bid = blockIdx.x;
  const int b = bid >> 4;
  const int g = (bid >> 2) & 3;
  const int rc = bid & 3;
  const int row0 = rc * 16;
  const int c0 = g * 64;

  const int ch = t >> 5;      // staging channel 0..7
  const int part = t & 31;    // staging lane within channel group
  const int p16 = part >> 4;  // 0/1: which of the two rows this lane covers
  const int seg = part & 15;  // float4 segment within row
  const int r = t >> 4;       // conv output row 0..15
  const int cg = t & 15;      // conv col group (cols cg*4 .. cg*4+3)

  // prologue: issue chunk-0 loads first so they overlap the LDS zero-fill
  float4 v[9];
  {
    const float* xsrc0 = x + ((size_t)(b * CIN + c0 + ch) * HW);
#pragma unroll
    for (int i = 0; i < 9; ++i) {
      const int grow = row0 - 1 + 2 * i + p16;
      if ((unsigned)grow < 64u)
        v[i] = *(const float4*)(xsrc0 + grow * 64 + seg * 4);
    }
  }
  __builtin_amdgcn_sched_barrier(0);  // keep loads issued here

  // zero once: out-of-image halo rows (rc=0 row 0 / rc=3 row 17) stay zero
  {
    float4 z4 = {0.0f, 0.0f, 0.0f, 0.0f};
    for (int i = t; i < 8 * TROWS * XS / 4; i += 256)
      *(float4*)&xs[i * 4] = z4;
  }

  float acc[8][4];
#pragma unroll
  for (int n = 0; n < 8; ++n)
#pragma unroll
    for (int j = 0; j < 4; ++j) acc[n][j] = 0.0f;

#pragma unroll 1
  for (int chunk = 0; chunk < 8; ++chunk) {
    const int cbase = c0 + chunk * 8;

    // ---- LDS free (zero-init done / previous compute done) ----
    __syncthreads();

    // ---- write staged registers to LDS (b128, aligned), pool partials ----
    float psum = 0.0f;
#pragma unroll
    for (int i = 0; i < 9; ++i) {
      const int row = 2 * i + p16;  // 0..17
      const int grow = row0 - 1 + row;
      if ((unsigned)grow < 64u) {
        *(float4*)&xs[(ch * TROWS + row) * XS + seg * 4] = v[i];
        if (row >= 1 && row <= 16)
          psum += (v[i].x + v[i].y) + (v[i].z + v[i].w);
      }
    }
#pragma unroll
    for (int off = 16; off > 0; off >>= 1)
      psum += __shfl_down(psum, off, 32);
    if (part == 0)
      poolpart[(b * 4 + rc) * 256 + cbase + ch] = psum;
    __syncthreads();

    // ---- prefetch next chunk into registers (latency hides under FMAs) ----
    if (chunk < 7) {
      const float* xsrc = x + ((size_t)(b * CIN + cbase + 8 + ch) * HW);
#pragma unroll
      for (int i = 0; i < 9; ++i) {
        const int grow = row0 - 1 + 2 * i + p16;
        if ((unsigned)grow < 64u)
          v[i] = *(const float4*)(xsrc + grow * 64 + seg * 4);
      }
    }
    __builtin_amdgcn_sched_barrier(0);  // do NOT sink these loads below

    // ---- compute: 8 ch x 3x3 x 8 filters x 4 cols ----
#pragma unroll
    for (int cc = 0; cc < 8; ++cc) {
      const float* fb = fT + (size_t)(cbase + cc) * 72;  // wave-uniform -> s_load
      const float* xrow = &xs[(cc * TROWS + r) * XS + cg * 4];
#pragma unroll
      for (int dy = 0; dy < 3; ++dy) {
        float4 a0 = *(const float4*)(xrow + dy * XS);   // single b128, aligned
        float wl = __shfl_up(a0.w, 1, 16);    // neighbor col 4cg-1 (DPP)
        float wr = __shfl_down(a0.x, 1, 16);  // neighbor col 4cg+4 (DPP)
        float w[6];
        w[0] = (cg == 0) ? 0.0f : wl;    // image left edge -> zero pad
        w[1] = a0.x; w[2] = a0.y; w[3] = a0.z; w[4] = a0.w;
        w[5] = (cg == 15) ? 0.0f : wr;   // image right edge -> zero pad
#pragma unroll
        for (int dx = 0; dx < 3; ++dx) {
#pragma unroll
          for (int n = 0; n < 8; ++n) {
            const float fv = fb[(dy * 3 + dx) * 8 + n];  // uniform (SGPR)
#pragma unroll
            for (int j = 0; j < 4; ++j)
              acc[n][j] = fmaf(w[j + dx], fv, acc[n][j]);
          }
        }
      }
    }
    // next iteration's top barrier protects the LDS overwrite
  }

  // write partial y for this channel-group: ypart[b][g][n][row][col]
#pragma unroll
  for (int n = 0; n < 8; ++n) {
    float* yp = ypart +
        ((size_t)(((b * 4 + g) * 8 + n) * 64 + row0 + r) * 64 + cg * 4);
    float4 v0 = {acc[n][0], acc[n][1], acc[n][2], acc[n][3]};
    *(float4*)(yp) = v0;
  }
}

// ---------------- K2: MLP + softmax -> mix [64][256][8] --------------------
__global__ __launch_bounds__(256) void mlp_kernel(
    const float* __restrict__ poolpart, const float* __restrict__ w1,
    const float* __restrict__ b1, const float* __restrict__ w2,
    const float* __restrict__ b2, float* __restrict__ mix) {
  __shared__ float pool_s[256];
  __shared__ float h_s[128];
  const int t = threadIdx.x;
  const int b = blockIdx.x;
  pool_s[t] = (poolpart[(b * 4 + 0) * 256 + t] +
               poolpart[(b * 4 + 1) * 256 + t] +
               poolpart[(b * 4 + 2) * 256 + t] +
               poolpart[(b * 4 + 3) * 256 + t]) * (1.0f / 4096.0f);
  __syncthreads();
  if (t < 128) {
    float a = b1[t];
    const float* wr = w1 + t * 256;
    for (int c = 0; c < 256; c += 4) {
      float4 wv = *(const float4*)(wr + c);
      a = fmaf(pool_s[c], wv.x, a);
      a = fmaf(pool_s[c + 1], wv.y, a);
      a = fmaf(pool_s[c + 2], wv.z, a);
      a = fmaf(pool_s[c + 3], wv.w, a);
    }
    h_s[t] = fmaxf(a, 0.0f);
  }
  __syncthreads();
  float m[8];
#pragma unroll
  for (int n = 0; n < 8; ++n) {
    float a = b2[t * 8 + n];
    const float* wr = w2 + (size_t)(t * 8 + n) * 128;
    for (int j = 0; j < 128; j += 4) {
      float4 wv = *(const float4*)(wr + j);
      a = fmaf(h_s[j], wv.x, a);
      a = fmaf(h_s[j + 1], wv.y, a);
      a = fmaf(h_s[j + 2], wv.z, a);
      a = fmaf(h_s[j + 3], wv.w, a);
    }
    m[n] = a;
  }
  float mx = m[0];
#pragma unroll
  for (int n = 1; n < 8; ++n) mx = fmaxf(mx, m[n]);
  float s = 0.0f;
#pragma unroll
  for (int n = 0; n < 8; ++n) {
    m[n] = __expf(m[n] - mx);
    s += m[n];
  }
  float inv = 1.0f / s;
#pragma unroll
  for (int n = 0; n < 8; ++n) mix[(size_t)(b * 256 + t) * 8 + n] = m[n] * inv;
}

// ---------------- K3: out[b][o][p] = sum_n mix[b][o][n] * y[b][n][p] -------
// v2: grid 512 (o-range split in two -> 2 blocks/CU, 8 waves/CU); mix read
// via wave-uniform global loads (scalarized to s_load, no LDS round-trip);
// nontemporal stores for the write-once 268 MB output.
// bid = ((b*4 + tile)*2 + oh). block 256.
__global__ __launch_bounds__(256, 4) void mix_conv_kernel(
    const float* __restrict__ ypart, const float* __restrict__ mix,
    float* __restrict__ out) {
  __shared__ float ys[8 * 1024];    // 32 KB
  const int t = threadIdx.x;
  const int bid = blockIdx.x;
  const int b = bid >> 3;
  const int tile = (bid >> 1) & 3;
  const int oh = bid & 1;           // which half of the o-range
  const int p0 = tile * 1024;

  const float* yb = ypart + (size_t)b * 4 * 8 * HW + p0;
  for (int i = t; i < 2048; i += 256) {  // 2048 float4 slots = 8 x 1024 floats
    int n = i >> 8;
    int pv = i & 255;
    const float* y0 = yb + n * HW + pv * 4;
    float4 a = *(const float4*)(y0);
    float4 c = *(const float4*)(y0 + 8 * HW);
    float4 d = *(const float4*)(y0 + 16 * HW);
    float4 e = *(const float4*)(y0 + 24 * HW);
    float4 rr = {a.x + c.x + d.x + e.x, a.y + c.y + d.y + e.y,
                 a.z + c.z + d.z + e.z, a.w + c.w + d.w + e.w};
    *(float4*)&ys[n * 1024 + pv * 4] = rr;
  }
  __syncthreads();

  float4 y4[8];
#pragma unroll
  for (int n = 0; n < 8; ++n) y4[n] = *(const float4*)&ys[n * 1024 + t * 4];

  const float* mixb = mix + ((size_t)b * 256 + oh * 128) * 8;
  float* op = out + ((size_t)b * COUT + oh * 128) * HW + p0 + t * 4;
#pragma unroll 2
  for (int o = 0; o < 128; ++o) {
    const float* mp = mixb + o * 8;          // wave-uniform -> s_load
    float4 ma = *(const float4*)(mp);
    float4 mb = *(const float4*)(mp + 4);
    float4 r;
    r.x = ma.x * y4[0].x; r.y = ma.x * y4[0].y;
    r.z = ma.x * y4[0].z; r.w = ma.x * y4[0].w;
    r.x = fmaf(ma.y, y4[1].x, r.x); r.y = fmaf(ma.y, y4[1].y, r.y);
    r.z = fmaf(ma.y, y4[1].z, r.z); r.w = fmaf(ma.y, y4[1].w, r.w);
    r.x = fmaf(ma.z, y4[2].x, r.x); r.y = fmaf(ma.z, y4[2].y, r.y);
    r.z = fmaf(ma.z, y4[2].z, r.z); r.w = fmaf(ma.z, y4[2].w, r.w);
    r.x = fmaf(ma.w, y4[3].x, r.x); r.y = fmaf(ma.w, y4[3].y, r.y);
    r.z = fmaf(ma.w, y4[3].z, r.z); r.w = fmaf(ma.w, y4[3].w, r.w);
    r.x = fmaf(mb.x, y4[4].x, r.x); r.y = fmaf(mb.x, y4[4].y, r.y);
    r.z = fmaf(mb.x, y4[4].z, r.z); r.w = fmaf(mb.x, y4[4].w, r.w);
    r.x = fmaf(mb.y, y4[5].x, r.x); r.y = fmaf(mb.y, y4[5].y, r.y);
    r.z = fmaf(mb.y, y4[5].z, r.z); r.w = fmaf(mb.y, y4[5].w, r.w);
    r.x = fmaf(mb.z, y4[6].x, r.x); r.y = fmaf(mb.z, y4[6].y, r.y);
    r.z = fmaf(mb.z, y4[6].z, r.z); r.w = fmaf(mb.z, y4[6].w, r.w);
    r.x = fmaf(mb.w, y4[7].x, r.x); r.y = fmaf(mb.w, y4[7].y, r.y);
    r.z = fmaf(mb.w, y4[7].z, r.z); r.w = fmaf(mb.w, y4[7].w, r.w);
    f32x4 rn = {r.x, r.y, r.z, r.w};
    __builtin_nontemporal_store(rn, (f32x4*)(op + (size_t)o * HW));
  }
}

// ---------------- launch ---------------------------------------------------
extern "C" void kernel_launch(void* const* d_in, const int* in_sizes, int n_in,
                              void* d_out, int out_size, void* d_ws,
                              size_t ws_size, hipStream_t stream) {
  const float* x  = (const float*)d_in[0];
  const float* w1 = (const float*)d_in[1];
  const float* b1 = (const float*)d_in[2];
  const float* w2 = (const float*)d_in[3];
  const float* b2 = (const float*)d_in[4];
  const float* bf = (const float*)d_in[5];
  float* out = (float*)d_out;

  char* ws = (char*)d_ws;
  float* ypart    = (float*)(ws);                     // 64*4*8*4096*4 = 33,554,432 B
  float* poolpart = (float*)(ws + 33554432);          // 64*4*256*4   =    262,144 B
  float* mixw     = (float*)(ws + 33554432 + 262144); // 64*256*8*4   =  2,097,152 B
  float* fT       = (float*)(ws + 33554432 + 262144 + 2097152);  // 73,728 B

  repack_filters<<<72, 256, 0, stream>>>(bf, fT);
  conv_pool_kernel<<<1024, 256, 0, stream>>>(x, fT, ypart, poolpart);
  mlp_kernel<<<64, 256, 0, stream>>>(poolpart, w1, b1, w2, b2, mixw);
  mix_conv_kernel<<<512, 256, 0, stream>>>(ypart, mixw, out);
}

// Round 5
// 599.988 us; speedup vs baseline: 1.0875x; 1.0875x over previous
//
#include <hip/hip_runtime.h>
#include <math.h>

#define CIN 256
#define COUT 256
#define NB 8
#define HID 128
#define HW 4096
#define BATCH 64

#define TROWS 18    // 16 output rows + 2 halo
#define XS 64       // row stride in LDS: no pads; col halo via lane shuffles
#define BUFN (8 * TROWS * XS)  // 9216 floats = 36,864 B per buffer

typedef float f32x4 __attribute__((ext_vector_type(4)));  // native vec for nt-store

// ---------------- K0: repack base_filters [n][c*9+d] -> fT[(c*9+d)*8+n] ----
__global__ __launch_bounds__(256) void repack_filters(
    const float* __restrict__ bf, float* __restrict__ fT) {
  int i = blockIdx.x * 256 + threadIdx.x;  // over 8*2304 = 18432
  if (i < 8 * 2304) {
    int n = i / 2304;
    int cd = i % 2304;
    fT[cd * 8 + n] = bf[i];
  }
}

// ---------------- K1: conv (x -> ypart) + pooling partials -----------------
// grid 1024: bid = b*16 + g*4 + rc. block 256, 2 blocks/CU (LDS 73.7KB)
// v5: global_load_lds double-buffered pipeline. v2-v4 proved any scheme
// holding a 36-VGPR prefetch across the FMA phase spills (RA caps at 64
// VGPR; WRITE_SIZE 235MB of scratch). DMA staging needs zero registers:
// issue chunk k+1 into buf B, s_waitcnt vmcnt(9) (9 newest stay in
// flight ACROSS the barrier), raw s_barrier, compute chunk k from buf A.
// LDS layout is linear [ch][row][64] == wave-uniform base + lane*16B slot
// order required by the DMA; read pattern identical to v3 (conflict-free).
__global__ __launch_bounds__(256) void conv_pool_kernel(
    const float* __restrict__ x, const float* __restrict__ fT,
    float* __restrict__ ypart, float* __restrict__ poolpart) {
  __shared__ float xs[2][BUFN];  // 73,728 B
  const int t = threadIdx.x;
  const int bid = blockIdx.x;
  const int b = bid >> 4;
  const int g = (bid >> 2) & 3;
  const int rc = bid & 3;
  const int row0 = rc * 16;
  const int c0 = g * 64;

  const int w = t >> 6;       // wave 0..3
  const int l = t & 63;       // lane
  const int ch = t >> 5;      // pool channel group 0..7
  const int part = t & 31;    // pool lane within channel group
  const int p16 = part >> 4;  // pool: which of two rows
  const int seg = part & 15;  // pool: float4 segment
  const int r = t >> 4;       // conv output row 0..15
  const int cg = t & 15;      // conv col group (cols cg*4 .. cg*4+3)

  // zero both buffers once: out-of-image halo rows (rc=0 row 0 / rc=3
  // row 17) are never DMA'd (lanes exec-masked) and must read as zero.
  {
    float* xsf = &xs[0][0];
    float4 z4 = {0.0f, 0.0f, 0.0f, 0.0f};
    for (int i = t; i < 2 * BUFN / 4; i += 256) *(float4*)&xsf[i * 4] = z4;
  }
  __syncthreads();  // zeros visible before any DMA lands

  // DMA one 8ch x 18row x 64col tile: 36 wave-instructions (9/wave), each
  // filling 64 consecutive 16B slots. Slot flat = w*576 + i*64 + l maps to
  // (ch, row, seg) of the linear [ch][18][64] layout; LDS base (w*9+i)*1024B
  // is wave-uniform, lane l lands at +l*16B (HW rule). Global src per-lane.
#define STAGE(bufsel, cb)                                                    \
  {                                                                          \
    _Pragma("unroll") for (int i = 0; i < 9; ++i) {                          \
      const int il = i * 64 + l;                                             \
      const int c1 = (il >= 288) ? 1 : 0; /* 288 = 18*16 slots/channel */    \
      const int chs = 2 * w + c1;                                            \
      const int rem = il - 288 * c1;                                         \
      const int rows_ = rem >> 4;                                            \
      const int segs_ = rem & 15;                                            \
      const int grow_ = row0 - 1 + rows_;                                    \
      if ((unsigned)grow_ < 64u) /* >=48/64 lanes active: always issues */   \
        __builtin_amdgcn_global_load_lds(                                    \
            (__attribute__((address_space(1))) unsigned int*)(               \
                x + ((size_t)(b * CIN + (cb) + chs) * HW + grow_ * 64 +      \
                     segs_ * 4)),                                            \
            (__attribute__((address_space(3))) unsigned int*)(               \
                &xs[bufsel][(w * 9 + i) * 256]),                             \
            16, 0, 0);                                                       \
    }                                                                        \
  }

  STAGE(0, c0);  // chunk 0 in flight

  float acc[8][4];
#pragma unroll
  for (int n = 0; n < 8; ++n)
#pragma unroll
    for (int j = 0; j < 4; ++j) acc[n][j] = 0.0f;

#pragma unroll 1
  for (int chunk = 0; chunk < 8; ++chunk) {
    const int cur = chunk & 1;
    const int cbase = c0 + chunk * 8;

    if (chunk < 7) {
      STAGE(cur ^ 1, cbase + 8);  // issue next chunk (9 loads stay in flight)
      asm volatile("s_waitcnt vmcnt(9)" ::: "memory");  // chunk-k DMA done
    } else {
      asm volatile("s_waitcnt vmcnt(0)" ::: "memory");
    }
    asm volatile("s_barrier" ::: "memory");  // B1: buf[cur] complete for all

    // ---- pool partials: read back own slots (conflict-free b128) ----
    float psum = 0.0f;
#pragma unroll
    for (int i = 0; i < 9; ++i) {
      const int row = 2 * i + p16;  // 0..17; pool only in-image rows 1..16
      if (row >= 1 && row <= 16) {
        float4 pv = *(const float4*)&xs[cur][(ch * TROWS + row) * XS + seg * 4];
        psum += (pv.x + pv.y) + (pv.z + pv.w);
      }
    }
#pragma unroll
    for (int off = 16; off > 0; off >>= 1)
      psum += __shfl_down(psum, off, 32);
    if (part == 0)
      poolpart[(b * 4 + rc) * 256 + cbase + ch] = psum;

    // ---- compute: 8 ch x 3x3 x 8 filters x 4 cols ----
#pragma unroll
    for (int cc = 0; cc < 8; ++cc) {
      const float* fb = fT + (size_t)(cbase + cc) * 72;  // uniform -> s_load
      const float* xrow = &xs[cur][(cc * TROWS + r) * XS + cg * 4];
#pragma unroll
      for (int dy = 0; dy < 3; ++dy) {
        float4 a0 = *(const float4*)(xrow + dy * XS);  // single b128, aligned
        float wl = __shfl_up(a0.w, 1, 16);    // neighbor col 4cg-1
        float wr = __shfl_down(a0.x, 1, 16);  // neighbor col 4cg+4
        float w6[6];
        w6[0] = (cg == 0) ? 0.0f : wl;   // image left edge -> zero pad
        w6[1] = a0.x; w6[2] = a0.y; w6[3] = a0.z; w6[4] = a0.w;
        w6[5] = (cg == 15) ? 0.0f : wr;  // image right edge -> zero pad
#pragma unroll
        for (int dx = 0; dx < 3; ++dx) {
#pragma unroll
          for (int n = 0; n < 8; ++n) {
            const float fv = fb[(dy * 3 + dx) * 8 + n];  // uniform (SGPR)
#pragma unroll
            for (int j = 0; j < 4; ++j)
              acc[n][j] = fmaf(w6[j + dx], fv, acc[n][j]);
          }
        }
      }
    }

    // B2: my ds_reads complete, then all waves done with buf[cur] ->
    // next iteration may DMA into it.
    asm volatile("s_waitcnt lgkmcnt(0)" ::: "memory");
    asm volatile("s_barrier" ::: "memory");
  }
#undef STAGE

  // write partial y for this channel-group: ypart[b][g][n][row][col]
#pragma unroll
  for (int n = 0; n < 8; ++n) {
    float* yp = ypart +
        ((size_t)(((b * 4 + g) * 8 + n) * 64 + row0 + r) * 64 + cg * 4);
    float4 v0 = {acc[n][0], acc[n][1], acc[n][2], acc[n][3]};
    *(float4*)(yp) = v0;
  }
}

// ---------------- K2: MLP + softmax -> mix [64][256][8] --------------------
__global__ __launch_bounds__(256) void mlp_kernel(
    const float* __restrict__ poolpart, const float* __restrict__ w1,
    const float* __restrict__ b1, const float* __restrict__ w2,
    const float* __restrict__ b2, float* __restrict__ mix) {
  __shared__ float pool_s[256];
  __shared__ float h_s[128];
  const int t = threadIdx.x;
  const int b = blockIdx.x;
  pool_s[t] = (poolpart[(b * 4 + 0) * 256 + t] +
               poolpart[(b * 4 + 1) * 256 + t] +
               poolpart[(b * 4 + 2) * 256 + t] +
               poolpart[(b * 4 + 3) * 256 + t]) * (1.0f / 4096.0f);
  __syncthreads();
  if (t < 128) {
    float a = b1[t];
    const float* wr = w1 + t * 256;
    for (int c = 0; c < 256; c += 4) {
      float4 wv = *(const float4*)(wr + c);
      a = fmaf(pool_s[c], wv.x, a);
      a = fmaf(pool_s[c + 1], wv.y, a);
      a = fmaf(pool_s[c + 2], wv.z, a);
      a = fmaf(pool_s[c + 3], wv.w, a);
    }
    h_s[t] = fmaxf(a, 0.0f);
  }
  __syncthreads();
  float m[8];
#pragma unroll
  for (int n = 0; n < 8; ++n) {
    float a = b2[t * 8 + n];
    const float* wr = w2 + (size_t)(t * 8 + n) * 128;
    for (int j = 0; j < 128; j += 4) {
      float4 wv = *(const float4*)(wr + j);
      a = fmaf(h_s[j], wv.x, a);
      a = fmaf(h_s[j + 1], wv.y, a);
      a = fmaf(h_s[j + 2], wv.z, a);
      a = fmaf(h_s[j + 3], wv.w, a);
    }
    m[n] = a;
  }
  float mx = m[0];
#pragma unroll
  for (int n = 1; n < 8; ++n) mx = fmaxf(mx, m[n]);
  float s = 0.0f;
#pragma unroll
  for (int n = 0; n < 8; ++n) {
    m[n] = __expf(m[n] - mx);
    s += m[n];
  }
  float inv = 1.0f / s;
#pragma unroll
  for (int n = 0; n < 8; ++n) mix[(size_t)(b * 256 + t) * 8 + n] = m[n] * inv;
}

// ---------------- K3: out[b][o][p] = sum_n mix[b][o][n] * y[b][n][p] -------
// grid 512 (o-range split in two -> 2 blocks/CU); mix read via wave-uniform
// global loads (scalarized); nontemporal stores for the write-once output.
__global__ __launch_bounds__(256, 4) void mix_conv_kernel(
    const float* __restrict__ ypart, const float* __restrict__ mix,
    float* __restrict__ out) {
  __shared__ float ys[8 * 1024];    // 32 KB
  const int t = threadIdx.x;
  const int bid = blockIdx.x;
  const int b = bid >> 3;
  const int tile = (bid >> 1) & 3;
  const int oh = bid & 1;           // which half of the o-range
  const int p0 = tile * 1024;

  const float* yb = ypart + (size_t)b * 4 * 8 * HW + p0;
  for (int i = t; i < 2048; i += 256) {  // 2048 float4 slots = 8 x 1024 floats
    int n = i >> 8;
    int pv = i & 255;
    const float* y0 = yb + n * HW + pv * 4;
    float4 a = *(const float4*)(y0);
    float4 c = *(const float4*)(y0 + 8 * HW);
    float4 d = *(const float4*)(y0 + 16 * HW);
    float4 e = *(const float4*)(y0 + 24 * HW);
    float4 rr = {a.x + c.x + d.x + e.x, a.y + c.y + d.y + e.y,
                 a.z + c.z + d.z + e.z, a.w + c.w + d.w + e.w};
    *(float4*)&ys[n * 1024 + pv * 4] = rr;
  }
  __syncthreads();

  float4 y4[8];
#pragma unroll
  for (int n = 0; n < 8; ++n) y4[n] = *(const float4*)&ys[n * 1024 + t * 4];

  const float* mixb = mix + ((size_t)b * 256 + oh * 128) * 8;
  float* op = out + ((size_t)b * COUT + oh * 128) * HW + p0 + t * 4;
#pragma unroll 2
  for (int o = 0; o < 128; ++o) {
    const float* mp = mixb + o * 8;          // wave-uniform -> s_load
    float4 ma = *(const float4*)(mp);
    float4 mb = *(const float4*)(mp + 4);
    float4 r;
    r.x = ma.x * y4[0].x; r.y = ma.x * y4[0].y;
    r.z = ma.x * y4[0].z; r.w = ma.x * y4[0].w;
    r.x = fmaf(ma.y, y4[1].x, r.x); r.y = fmaf(ma.y, y4[1].y, r.y);
    r.z = fmaf(ma.y, y4[1].z, r.z); r.w = fmaf(ma.y, y4[1].w, r.w);
    r.x = fmaf(ma.z, y4[2].x, r.x); r.y = fmaf(ma.z, y4[2].y, r.y);
    r.z = fmaf(ma.z, y4[2].z, r.z); r.w = fmaf(ma.z, y4[2].w, r.w);
    r.x = fmaf(ma.w, y4[3].x, r.x); r.y = fmaf(ma.w, y4[3].y, r.y);
    r.z = fmaf(ma.w, y4[3].z, r.z); r.w = fmaf(ma.w, y4[3].w, r.w);
    r.x = fmaf(mb.x, y4[4].x, r.x); r.y = fmaf(mb.x, y4[4].y, r.y);
    r.z = fmaf(mb.x, y4[4].z, r.z); r.w = fmaf(mb.x, y4[4].w, r.w);
    r.x = fmaf(mb.y, y4[5].x, r.x); r.y = fmaf(mb.y, y4[5].y, r.y);
    r.z = fmaf(mb.y, y4[5].z, r.z); r.w = fmaf(mb.y, y4[5].w, r.w);
    r.x = fmaf(mb.z, y4[6].x, r.x); r.y = fmaf(mb.z, y4[6].y, r.y);
    r.z = fmaf(mb.z, y4[6].z, r.z); r.w = fmaf(mb.z, y4[6].w, r.w);
    r.x = fmaf(mb.w, y4[7].x, r.x); r.y = fmaf(mb.w, y4[7].y, r.y);
    r.z = fmaf(mb.w, y4[7].z, r.z); r.w = fmaf(mb.w, y4[7].w, r.w);
    f32x4 rn = {r.x, r.y, r.z, r.w};
    __builtin_nontemporal_store(rn, (f32x4*)(op + (size_t)o * HW));
  }
}

// ---------------- launch ---------------------------------------------------
extern "C" void kernel_launch(void* const* d_in, const int* in_sizes, int n_in,
                              void* d_out, int out_size, void* d_ws,
                              size_t ws_size, hipStream_t stream) {
  const float* x  = (const float*)d_in[0];
  const float* w1 = (const float*)d_in[1];
  const float* b1 = (const float*)d_in[2];
  const float* w2 = (const float*)d_in[3];
  const float* b2 = (const float*)d_in[4];
  const float* bf = (const float*)d_in[5];
  float* out = (float*)d_out;

  char* ws = (char*)d_ws;
  float* ypart    = (float*)(ws);                     // 64*4*8*4096*4 = 33,554,432 B
  float* poolpart = (float*)(ws + 33554432);          // 64*4*256*4   =    262,144 B
  float* mixw     = (float*)(ws + 33554432 + 262144); // 64*256*8*4   =  2,097,152 B
  float* fT       = (float*)(ws + 33554432 + 262144 + 2097152);  // 73,728 B

  repack_filters<<<72, 256, 0, stream>>>(bf, fT);
  conv_pool_kernel<<<1024, 256, 0, stream>>>(x, fT, ypart, poolpart);
  mlp_kernel<<<64, 256, 0, stream>>>(poolpart, w1, b1, w2, b2, mixw);
  mix_conv_kernel<<<512, 256, 0, stream>>>(ypart, mixw, out);
}